// Round 7
// baseline (1546.488 us; speedup 1.0000x reference)
//
#include <hip/hip_runtime.h>
#include <stdint.h>

#define FDIM 128
constexpr int EP_NONE = 0, EP_RELU = 1, EP_FILM = 2, EP_LNRELU = 3;

typedef __attribute__((ext_vector_type(8))) short short8v;  // 8 bf16
typedef __attribute__((ext_vector_type(4))) float f32x4;
typedef __attribute__((ext_vector_type(4))) unsigned int u32x4;

struct Srcs { const float* p[5]; };
struct WPtrs { const float* p[14]; };

__device__ __forceinline__ short f2bf(float f) {
  unsigned u = __float_as_uint(f);
  u = (u + 0x7fffu + ((u >> 16) & 1u)) >> 16;
  return (short)u;
}
__device__ __forceinline__ float bf2f(short s) {
  return __uint_as_float(((unsigned)(unsigned short)s) << 16);
}

// async global->LDS, 16B per lane (dest = wave-uniform base + lane*16)
__device__ __forceinline__ void gload16(const float* g, float* l) {
  __builtin_amdgcn_global_load_lds(
      (const __attribute__((address_space(1))) void*)g,
      (__attribute__((address_space(3))) void*)l, 16, 0, 0);
}

#define VM_WAIT8 do { asm volatile("s_waitcnt vmcnt(8)" ::: "memory"); \
                      __builtin_amdgcn_sched_barrier(0); } while (0)
#define VM_WAIT0 do { asm volatile("s_waitcnt vmcnt(0)" ::: "memory"); \
                      __builtin_amdgcn_sched_barrier(0); } while (0)

// ---------------- CSR build ----------------

__global__ __launch_bounds__(256)
void k_hist(const int* __restrict__ dst, int* __restrict__ cnt, int E) {
  int e = blockIdx.x * 256 + threadIdx.x;
  if (e < E) atomicAdd(&cnt[dst[e]], 1);
}

__global__ __launch_bounds__(1024)
void k_scan_block(const int* __restrict__ cnt, int* __restrict__ scanned,
                  int* __restrict__ partials, int n) {
  __shared__ int sd[1024];
  int tid = threadIdx.x;
  int i = blockIdx.x * 1024 + tid;
  int v = (i < n) ? cnt[i] : 0;
  sd[tid] = v; __syncthreads();
  for (int off = 1; off < 1024; off <<= 1) {
    int t = (tid >= off) ? sd[tid - off] : 0;
    __syncthreads();
    sd[tid] += t;
    __syncthreads();
  }
  if (i < n) scanned[i] = sd[tid] - v;
  if (tid == 1023) partials[blockIdx.x] = sd[1023];
}

__global__ __launch_bounds__(128)
void k_scan_small(const int* __restrict__ partials, int* __restrict__ p2, int nb) {
  __shared__ int sd[128];
  int tid = threadIdx.x;
  int v = (tid < nb) ? partials[tid] : 0;
  sd[tid] = v; __syncthreads();
  for (int off = 1; off < 128; off <<= 1) {
    int t = (tid >= off) ? sd[tid - off] : 0;
    __syncthreads();
    sd[tid] += t;
    __syncthreads();
  }
  p2[tid] = sd[tid] - v;
}

__global__ __launch_bounds__(256)
void k_finalize(const int* __restrict__ scanned, const int* __restrict__ p2,
                int* __restrict__ indptr, int* __restrict__ cursor, int n, int E) {
  int i = blockIdx.x * 256 + threadIdx.x;
  if (i < n) {
    int v = scanned[i] + p2[i >> 10];
    indptr[i] = v;
    cursor[i] = v;
  }
  if (i == 0) indptr[n] = E;
}

__global__ __launch_bounds__(256)
void k_scatter(const int* __restrict__ src, const int* __restrict__ dst,
               int* __restrict__ cursor, int* __restrict__ eids, int E) {
  int e = blockIdx.x * 256 + threadIdx.x;
  if (e < E) {
    int p = atomicAdd(&cursor[dst[e]], 1);
    eids[p] = src[e];
  }
}

// ---------------- aggregation: z = h + segment_sum(h[src], dst) ----------------
// one wave per node; lane covers 2 cols; 16 gathers in flight (clamped idx,
// predicated add) -> no scalar tail loop

__global__ __launch_bounds__(256)
void k_aggr(const float* __restrict__ h, const int* __restrict__ indptr,
            const int* __restrict__ eids, float* __restrict__ z, int n) {
  int lane = threadIdx.x & 63;
  int node = blockIdx.x * 4 + (threadIdx.x >> 6);
  if (node >= n) return;
  float2 acc = *(const float2*)&h[(size_t)node * FDIM + lane * 2];
  int s = indptr[node], e = indptr[node + 1];
  for (int base = s; base < e; base += 64) {
    int cnt = min(64, e - base);
    int eid = (base + lane < e) ? eids[base + lane] : 0;
    for (int j = 0; j < cnt; j += 16) {
      float2 v[16];
      #pragma unroll
      for (int t = 0; t < 16; ++t) {
        int idx = j + t;
        int sn = __shfl(eid, idx < cnt ? idx : cnt - 1, 64);
        v[t] = *(const float2*)&h[(size_t)sn * FDIM + lane * 2];
      }
      #pragma unroll
      for (int t = 0; t < 16; ++t)
        if (j + t < cnt) { acc.x += v[t].x; acc.y += v[t].y; }
    }
  }
  *(float2*)&z[(size_t)node * FDIM + lane * 2] = acc;
}

// ---------------- weight pre-transpose: W[k][c] f32 -> Wt[m][c][k] bf16 hi/lo ----------------

__global__ __launch_bounds__(256)
void k_wt(WPtrs wp, short* __restrict__ wtHi, short* __restrict__ wtLo) {
  const int m = blockIdx.x;
  const float* __restrict__ W = wp.p[m];
  const int t = threadIdx.x;
  #pragma unroll
  for (int u = 0; u < 8; ++u) {
    int chunk = t + u * 256;       // 0..2047 = c*16 + kc
    int c = chunk >> 4, kc = chunk & 15;
    short8v hi, lo;
    #pragma unroll
    for (int j = 0; j < 8; ++j) {
      float w = W[(kc * 8 + j) * FDIM + c];
      short h = f2bf(w);
      hi[j] = h;
      lo[j] = f2bf(w - bf2f(h));
    }
    int off = m * 16384 + c * FDIM + kc * 8;
    *(short8v*)(wtHi + off) = hi;
    *(short8v*)(wtLo + off) = lo;
  }
}

// ---------------- fused 2-layer MLP, async-staged, wave-private LDS ----------------
// BM=64 (4 waves x 16 rows, each wave owns its rows end-to-end -> NO barriers).
// Stage: global_load_lds 16B x8 per wave per source, double-buffered across
// sources, s_waitcnt vmcnt(8) counted (FIFO makes the count robust).
// LDS layout [16][128] f32 with granule XOR swizzle: lds[r][g] = A[row][g^(r&7)]
// (pre-swizzled global source; reads ds_read_b128 at granule ga^(r&7): 2-way,free).
// Stage-1 out -> same-wave LDS region (bf16 hi|lo packed u32, same swizzle) ->
// stage-2 GEMM -> epilogue2 -> global. hi/lo 3-term split = ~f32 accuracy.
// C/D frag: col = lane&15, row = 4*(lane>>4)+reg.

template<int NSRC, int EPI1, int EPI2>
__global__ __launch_bounds__(256, 2)
void k_mlp(Srcs srcs, const short* __restrict__ wtHi, const short* __restrict__ wtLo,
           int m0, int m1, const float* __restrict__ b1, const float* __restrict__ b2,
           float* __restrict__ out, int n,
           const int* __restrict__ bvec, const float* __restrict__ gam,
           const float* __restrict__ bet, int conv,
           const float* __restrict__ lng, const float* __restrict__ lnb) {
  __shared__ float lds[2][4][16][FDIM];   // 64 KB, wave-private 8KB regions

  const int tid = threadIdx.x;
  const int lane = tid & 63;
  const int w = tid >> 6;
  const int lr = lane & 15;
  const int lg = lane >> 4;
  const int row0w = blockIdx.x * 64 + w * 16;   // wave's first global row

  float* Lb0 = &lds[0][w][0][0];
  float* Lb1 = &lds[1][w][0][0];

  // stage this wave's 16 rows of A into Lw (8 x 1KB async ops)
  auto STAGE = [&](const float* __restrict__ A, float* Lw) {
    const int rl2 = lane >> 5;          // row within pair
    const int g = lane & 31;            // 16B granule 0..31
    #pragma unroll
    for (int t = 0; t < 8; ++t) {
      const int rl = t * 2 + rl2;       // wave-local row 0..15
      const int grow = min(row0w + rl, n - 1);
      const int gs = g ^ (rl & 7);      // pre-swizzled source granule
      gload16(A + (size_t)grow * FDIM + gs * 4, Lw + t * 256);
    }
  };

  auto COMPUTE = [&](const float* Lw, int wbase, f32x4 (&acc)[8]) {
    #pragma unroll
    for (int k = 0; k < 4; ++k) {
      const int ga = k * 8 + lg * 2;
      const float4 a0 = *(const float4*)&Lw[lr * FDIM + ((ga ^ (lr & 7)) << 2)];
      const float4 a1 = *(const float4*)&Lw[lr * FDIM + (((ga + 1) ^ (lr & 7)) << 2)];
      const float vv[8] = {a0.x, a0.y, a0.z, a0.w, a1.x, a1.y, a1.z, a1.w};
      short8v ah, al;
      #pragma unroll
      for (int j = 0; j < 8; ++j) {
        short h = f2bf(vv[j]);
        ah[j] = h;
        al[j] = f2bf(vv[j] - bf2f(h));
      }
      #pragma unroll
      for (int f = 0; f < 8; ++f) {
        const int boff = wbase + (f * 16 + lr) * FDIM + k * 32 + lg * 8;
        short8v bh = *(const short8v*)(wtHi + boff);
        short8v bl = *(const short8v*)(wtLo + boff);
        acc[f] = __builtin_amdgcn_mfma_f32_16x16x32_bf16(ah, bh, acc[f], 0, 0, 0);
        acc[f] = __builtin_amdgcn_mfma_f32_16x16x32_bf16(al, bh, acc[f], 0, 0, 0);
        acc[f] = __builtin_amdgcn_mfma_f32_16x16x32_bf16(ah, bl, acc[f], 0, 0, 0);
      }
    }
  };

  f32x4 acc[8];
  #pragma unroll
  for (int f = 0; f < 8; ++f) acc[f] = (f32x4){0.f, 0.f, 0.f, 0.f};

  // ---- stage-1 pipeline over sources ----
  STAGE(srcs.p[0], Lb0);
  if constexpr (NSRC >= 2) STAGE(srcs.p[1], Lb1);

  #pragma unroll
  for (int js = 0; js < NSRC; ++js) {
    if (js < NSRC - 1) { VM_WAIT8; } else { VM_WAIT0; }
    COMPUTE((js & 1) ? Lb1 : Lb0, (m0 + js) * 16384, acc);
    __builtin_amdgcn_sched_barrier(0);
    if (js + 2 < NSRC) STAGE(srcs.p[js + 2], (js & 1) ? Lb1 : Lb0);
  }

  // ---- epilogue 1 (bias + ReLU / LN+ReLU) -> packed interm in free buffer ----
  unsigned int* Ib = (unsigned int*)((NSRC & 1) ? Lb1 : Lb0);
  {
    float bb[8];
    #pragma unroll
    for (int f = 0; f < 8; ++f) bb[f] = b1[f * 16 + lr];
    #pragma unroll
    for (int f = 0; f < 8; ++f)
      #pragma unroll
      for (int i = 0; i < 4; ++i) acc[f][i] += bb[f];

    if constexpr (EPI1 == EP_LNRELU) {
      float sm[4] = {0.f, 0.f, 0.f, 0.f}, sq[4] = {0.f, 0.f, 0.f, 0.f};
      #pragma unroll
      for (int f = 0; f < 8; ++f)
        #pragma unroll
        for (int i = 0; i < 4; ++i) {
          float v = acc[f][i];
          sm[i] += v; sq[i] += v * v;
        }
      #pragma unroll
      for (int m = 1; m < 16; m <<= 1)
        #pragma unroll
        for (int i = 0; i < 4; ++i) {
          sm[i] += __shfl_xor(sm[i], m, 64);
          sq[i] += __shfl_xor(sq[i], m, 64);
        }
      float gg[8], bn[8];
      #pragma unroll
      for (int f = 0; f < 8; ++f) { gg[f] = lng[f * 16 + lr]; bn[f] = lnb[f * 16 + lr]; }
      #pragma unroll
      for (int i = 0; i < 4; ++i) {
        const float mu = sm[i] * (1.f / FDIM);
        const float var = sq[i] * (1.f / FDIM) - mu * mu;
        const float rs = rsqrtf(var + 1e-5f);
        #pragma unroll
        for (int f = 0; f < 8; ++f)
          acc[f][i] = fmaxf((acc[f][i] - mu) * rs * gg[f] + bn[f], 0.f);
      }
    } else {  // EP_RELU
      #pragma unroll
      for (int f = 0; f < 8; ++f)
        #pragma unroll
        for (int i = 0; i < 4; ++i) acc[f][i] = fmaxf(acc[f][i], 0.f);
    }

    // pack hi|lo and store swizzled (wave-private; DS ops in-order, no barrier)
    #pragma unroll
    for (int f = 0; f < 8; ++f)
      #pragma unroll
      for (int i = 0; i < 4; ++i) {
        float v = acc[f][i];
        short hi = f2bf(v);
        short lo = f2bf(v - bf2f(hi));
        unsigned pk = (unsigned)(unsigned short)hi | ((unsigned)(unsigned short)lo << 16);
        const int r = 4 * lg + i;
        const int c = f * 16 + lr;
        Ib[r * FDIM + ((((c >> 2) ^ (r & 7)) << 2) | (c & 3))] = pk;
      }
  }

  // ---- stage 2: interm @ W[m1] ----
  f32x4 acc2[8];
  #pragma unroll
  for (int f = 0; f < 8; ++f) acc2[f] = (f32x4){0.f, 0.f, 0.f, 0.f};

  const int wbase2 = m1 * 16384;
  #pragma unroll
  for (int k = 0; k < 4; ++k) {
    const int ga = k * 8 + lg * 2;
    u32x4 u0 = *(const u32x4*)&Ib[lr * FDIM + ((ga ^ (lr & 7)) << 2)];
    u32x4 u1 = *(const u32x4*)&Ib[lr * FDIM + (((ga + 1) ^ (lr & 7)) << 2)];
    short8v ah, al;
    #pragma unroll
    for (int j = 0; j < 4; ++j) {
      ah[j]     = (short)(u0[j] & 0xffffu);
      al[j]     = (short)(u0[j] >> 16);
      ah[j + 4] = (short)(u1[j] & 0xffffu);
      al[j + 4] = (short)(u1[j] >> 16);
    }
    #pragma unroll
    for (int f = 0; f < 8; ++f) {
      const int boff = wbase2 + (f * 16 + lr) * FDIM + k * 32 + lg * 8;
      short8v bh = *(const short8v*)(wtHi + boff);
      short8v bl = *(const short8v*)(wtLo + boff);
      acc2[f] = __builtin_amdgcn_mfma_f32_16x16x32_bf16(ah, bh, acc2[f], 0, 0, 0);
      acc2[f] = __builtin_amdgcn_mfma_f32_16x16x32_bf16(al, bh, acc2[f], 0, 0, 0);
      acc2[f] = __builtin_amdgcn_mfma_f32_16x16x32_bf16(ah, bl, acc2[f], 0, 0, 0);
    }
  }

  // ---- epilogue 2 -> global ----
  {
    float bb[8];
    #pragma unroll
    for (int f = 0; f < 8; ++f) bb[f] = b2[f * 16 + lr];
    #pragma unroll
    for (int i = 0; i < 4; ++i) {
      const int r = row0w + 4 * lg + i;
      if (r >= n) continue;
      float g = 1.f, be = 0.f;
      if constexpr (EPI2 == EP_FILM) {
        int b = bvec[r];
        g = gam[b * 3 + conv];
        be = bet[b * 3 + conv];
      }
      #pragma unroll
      for (int f = 0; f < 8; ++f) {
        float o = acc2[f][i] + bb[f];
        if constexpr (EPI2 == EP_RELU) o = fmaxf(o, 0.f);
        if constexpr (EPI2 == EP_FILM) o = o * g + be;
        out[(size_t)r * FDIM + f * 16 + lr] = o;
      }
    }
  }
}

// ---------------- launch ----------------

extern "C" void kernel_launch(void* const* d_in, const int* in_sizes, int n_in,
                              void* d_out, int out_size, void* d_ws, size_t ws_size,
                              hipStream_t stream) {
  const float* x       = (const float*)d_in[0];
  const int*   eidx    = (const int*)d_in[1];
  const int*   bvec    = (const int*)d_in[2];
  const float* gam     = (const float*)d_in[3];
  const float* bet     = (const float*)d_in[4];
  const float* pre_W0  = (const float*)d_in[5];
  const float* pre_b0  = (const float*)d_in[6];
  const float* pre_W1  = (const float*)d_in[7];
  const float* pre_b1  = (const float*)d_in[8];
  const float* gin_W   = (const float*)d_in[9];
  const float* gin_b   = (const float*)d_in[10];
  const float* post_W0 = (const float*)d_in[11];
  const float* post_b0 = (const float*)d_in[12];
  const float* lng     = (const float*)d_in[13];
  const float* lnb     = (const float*)d_in[14];
  const float* post_W1 = (const float*)d_in[15];
  const float* post_b1 = (const float*)d_in[16];

  const int n = in_sizes[0] / FDIM;
  const int E = in_sizes[1] / 2;
  const int* esrc = eidx;
  const int* edst = eidx + E;
  float* out = (float*)d_out;

  // Workspace: h0..h3 (4*NF f32) + CSR ints + wt tables. zb aliases d_out.
  const size_t NF = (size_t)n * FDIM;
  float* fws = (float*)d_ws;
  float* h0  = fws;
  float* h1  = fws + NF;
  float* h2  = fws + 2 * NF;
  float* h3  = fws + 3 * NF;
  float* zb  = out;
  int* iws      = (int*)(fws + 4 * NF);
  int* counts   = iws;               // n
  int* scanned  = iws + n;           // n
  int* indptr   = iws + 2 * n;       // n+1
  int* cursor   = iws + 3 * n + 1;   // n
  int* partials = iws + 4 * n + 1;   // 128
  int* p2       = partials + 128;    // 128
  int* eids     = p2 + 128;          // E
  uintptr_t wtb = ((uintptr_t)(eids + E) + 15) & ~(uintptr_t)15;
  short* wtHi = (short*)wtb;         // 14*16384 bf16
  short* wtLo = wtHi + 14 * 16384;

  // weight pre-transpose
  WPtrs wp;
  wp.p[0] = pre_W0;
  wp.p[1] = pre_W1;
  for (int i = 0; i < 6; ++i) wp.p[2 + i] = gin_W + (size_t)i * 16384;
  for (int j = 0; j < 5; ++j) wp.p[8 + j] = post_W0 + (size_t)j * 16384;
  wp.p[13] = post_W1;
  k_wt<<<14, 256, 0, stream>>>(wp, wtHi, wtLo);

  // CSR build (by dst)
  hipMemsetAsync(counts, 0, (size_t)n * sizeof(int), stream);
  k_hist<<<(E + 255) / 256, 256, 0, stream>>>(edst, counts, E);
  const int nb = (n + 1023) / 1024;
  k_scan_block<<<nb, 1024, 0, stream>>>(counts, scanned, partials, n);
  k_scan_small<<<1, 128, 0, stream>>>(partials, p2, nb);
  k_finalize<<<(n + 255) / 256, 256, 0, stream>>>(scanned, p2, indptr, cursor, n, E);
  k_scatter<<<(E + 255) / 256, 256, 0, stream>>>(esrc, edst, cursor, eids, E);

  const int gb = (n + 63) / 64;

  // pre MLP fused: h0 = (relu(x@W0+b0))@W1+b1
  Srcs sx{{x, nullptr, nullptr, nullptr, nullptr}};
  k_mlp<1, EP_RELU, EP_NONE><<<gb, 256, 0, stream>>>(
      sx, wtHi, wtLo, 0, 1, pre_b0, pre_b1, h0, n,
      nullptr, nullptr, nullptr, 0, nullptr, nullptr);

  // GIN convs fused (GEMM1+ReLU+GEMM2+FiLM)
  float* hprev = h0;
  float* houts[3] = {h1, h2, h3};
  for (int i = 0; i < 3; ++i) {
    k_aggr<<<(n + 3) / 4, 256, 0, stream>>>(hprev, indptr, eids, zb, n);
    Srcs sz{{zb, nullptr, nullptr, nullptr, nullptr}};
    k_mlp<1, EP_RELU, EP_FILM><<<gb, 256, 0, stream>>>(
        sz, wtHi, wtLo, 2 + 2 * i, 3 + 2 * i,
        gin_b + (size_t)(2 * i) * FDIM, gin_b + (size_t)(2 * i + 1) * FDIM,
        houts[i], n, bvec, gam, bet, i, nullptr, nullptr);
    hprev = houts[i];
  }

  // post fused: out = (relu(LN(concat@W0+b0)))@W1+b1
  Srcs sj{{x, h0, h1, h2, h3}};
  k_mlp<5, EP_LNRELU, EP_NONE><<<gb, 256, 0, stream>>>(
      sj, wtHi, wtLo, 8, 13, post_b0, post_b1, out, n,
      nullptr, nullptr, nullptr, 0, lng, lnb);
}